// Round 1
// 500.560 us; speedup vs baseline: 1.0823x; 1.0823x over previous
//
#include <hip/hip_runtime.h>
#include <stdint.h>

// GEMM: C[M,N] = X[M,K] * W[N,K]^T + bias, group-dequantized W (group=64 along K).
// R5: structural rewrite of the GEMM to the 256^2 deep-pipeline template
// (T1 XCD swizzle + T2 conflict-free LDS swizzle + T3/T4 counted-vmcnt
// 4-phase groups + T5 setprio). Previous 128^2 2-barrier loop was at its
// ~900 TF structural ceiling (MfmaUtil 42.6%, vmcnt(0) drain per K-step).
// Schedule: tile t consumed from buf[t&1] in 4 phases (mh0/ks0, mh1/ks0,
// mh0/ks1, mh1/ks1); tile t+1 staged one unit/phase into buf[~t&1]
// (A-kh0, B-kh0, A-kh1, B-kh1); s_waitcnt vmcnt(4) every 2 phases retires
// exactly the 2 units needed next, keeping 4 loads in flight. vmcnt(0)
// only in the peeled last tile. cvt kernel deliberately unchanged this
// round (isolate the GEMM delta; ~244us of total is non-GEMM).

typedef __attribute__((ext_vector_type(8))) short short8;       // 8 bf16 = 4 VGPRs
typedef __attribute__((ext_vector_type(8))) unsigned short ushort8;
typedef __attribute__((ext_vector_type(4))) float f32x4;
typedef __attribute__((ext_vector_type(16))) float f32x16;
typedef __attribute__((ext_vector_type(4))) float float4v;
typedef __attribute__((ext_vector_type(4))) int int4v;

typedef __attribute__((address_space(1))) void g_void;
typedef __attribute__((address_space(3))) void l_void;

__device__ __forceinline__ unsigned short f2bf(float f) {
  union { float f; unsigned int u; } v; v.f = f;
  unsigned int r = v.u + 0x7FFFu + ((v.u >> 16) & 1u);  // round-to-nearest-even
  return (unsigned short)(r >> 16);
}

__device__ __forceinline__ void async_copy16(const void* g, void* l) {
  __builtin_amdgcn_global_load_lds((const g_void*)g, (l_void*)l, 16, 0, 0);
}

// barrier that the compiler cannot move LDS ops across, WITHOUT the
// vmcnt(0)+lgkmcnt(0) drain __syncthreads() forces.
__device__ __forceinline__ void wg_barrier() {
  asm volatile("" ::: "memory");
  __builtin_amdgcn_s_barrier();
  asm volatile("" ::: "memory");
}

#define WAIT_VMCNT(N) asm volatile("s_waitcnt vmcnt(" #N ")" ::: "memory")

// ---- fused conversion: X fp32->bf16 and W int32*scale->bf16, 8 elem/thread ----
__global__ __launch_bounds__(256) void cvt_kernel(
    const float* __restrict__ x, const int* __restrict__ w,
    const float* __restrict__ s, unsigned short* __restrict__ ox,
    unsigned short* __restrict__ ow, int n8x, int n8w, int gx) {
  if ((int)blockIdx.x < gx) {
    int t = blockIdx.x * 256 + threadIdx.x;
    if (t >= n8x) return;
    const float4v* xp = (const float4v*)x + (size_t)t * 2;
    float4v a = xp[0], b = xp[1];
    ushort8 r;
    r[0] = f2bf(a[0]); r[1] = f2bf(a[1]); r[2] = f2bf(a[2]); r[3] = f2bf(a[3]);
    r[4] = f2bf(b[0]); r[5] = f2bf(b[1]); r[6] = f2bf(b[2]); r[7] = f2bf(b[3]);
    *(ushort8*)(ox + (size_t)t * 8) = r;
  } else {
    int t = ((int)blockIdx.x - gx) * 256 + threadIdx.x;
    if (t >= n8w) return;
    const int4v* wp = (const int4v*)w + (size_t)t * 2;
    int4v q0 = wp[0], q1 = wp[1];
    float sc = s[t >> 3];  // GROUP_SIZE=64 = 8 threads x 8 elems
    ushort8 r;
    r[0] = f2bf((float)q0[0] * sc); r[1] = f2bf((float)q0[1] * sc);
    r[2] = f2bf((float)q0[2] * sc); r[3] = f2bf((float)q0[3] * sc);
    r[4] = f2bf((float)q1[0] * sc); r[5] = f2bf((float)q1[1] * sc);
    r[6] = f2bf((float)q1[2] * sc); r[7] = f2bf((float)q1[3] * sc);
    *(ushort8*)(ow + (size_t)t * 8) = r;
  }
}

// ---- main GEMM: 256x256 tile, BK=64, 8 waves, 4-phase counted-vmcnt ----
// LDS (128 KiB): A bufs [2][2kh][256 rows][32k] at 0..64K, B same at 64K..128K.
// Unit = one (buf,op,kh) slab of 16 KiB, staged by 2 global_load_lds/thread.
// Chunk swizzle: physical 16B chunk pc holds logical chunk pc ^ ((row>>1)&3)
// (involution; applied to the per-lane GLOBAL source on the write side since
// global_load_lds dests are linear, and to the ds_read address on the read
// side). Fragment reads then land 2 lanes/bank = conflict-free on CDNA4.

#define MF(a, b, c) __builtin_amdgcn_mfma_f32_16x16x32_bf16(a, b, c, 0, 0, 0)

#define LDA(base, mh) do {                              \
    const unsigned char* _p = (base) + aoff + (mh) * 4096; \
    av0 = *(const short8*)(_p);                         \
    av1 = *(const short8*)(_p + 1024);                  \
    av2 = *(const short8*)(_p + 2048);                  \
    av3 = *(const short8*)(_p + 3072);                  \
  } while (0)

#define LDB(base) do {                                  \
    const unsigned char* _p = (base) + boff;            \
    bv0 = *(const short8*)(_p);                         \
    bv1 = *(const short8*)(_p + 1024);                  \
    bv2 = *(const short8*)(_p + 2048);                  \
    bv3 = *(const short8*)(_p + 3072);                  \
  } while (0)

#define MM16(mb) do {                                           \
    acc[(mb)+0][0] = MF(av0, bv0, acc[(mb)+0][0]);              \
    acc[(mb)+0][1] = MF(av0, bv1, acc[(mb)+0][1]);              \
    acc[(mb)+0][2] = MF(av0, bv2, acc[(mb)+0][2]);              \
    acc[(mb)+0][3] = MF(av0, bv3, acc[(mb)+0][3]);              \
    acc[(mb)+1][0] = MF(av1, bv0, acc[(mb)+1][0]);              \
    acc[(mb)+1][1] = MF(av1, bv1, acc[(mb)+1][1]);              \
    acc[(mb)+1][2] = MF(av1, bv2, acc[(mb)+1][2]);              \
    acc[(mb)+1][3] = MF(av1, bv3, acc[(mb)+1][3]);              \
    acc[(mb)+2][0] = MF(av2, bv0, acc[(mb)+2][0]);              \
    acc[(mb)+2][1] = MF(av2, bv1, acc[(mb)+2][1]);              \
    acc[(mb)+2][2] = MF(av2, bv2, acc[(mb)+2][2]);              \
    acc[(mb)+2][3] = MF(av2, bv3, acc[(mb)+2][3]);              \
    acc[(mb)+3][0] = MF(av3, bv0, acc[(mb)+3][0]);              \
    acc[(mb)+3][1] = MF(av3, bv1, acc[(mb)+3][1]);              \
    acc[(mb)+3][2] = MF(av3, bv2, acc[(mb)+3][2]);              \
    acc[(mb)+3][3] = MF(av3, bv3, acc[(mb)+3][3]);              \
  } while (0)

#define PRIO1 __builtin_amdgcn_s_setprio(1)
#define PRIO0 __builtin_amdgcn_s_setprio(0)

__device__ __forceinline__ void stage2(const unsigned short* src, int rstride,
                                       unsigned char* dst) {
  async_copy16(src, dst);                    // rows [0,128)
  async_copy16(src + rstride, dst + 8192);   // rows [128,256)
}

__global__ __launch_bounds__(512, 2) void gemm_8p(
    const unsigned short* __restrict__ Xb,  // bf16 [M][K]
    const unsigned short* __restrict__ Wb,  // bf16 [N][K]
    const float* __restrict__ bias,
    float* __restrict__ C, int M, int N, int K) {
  __shared__ __align__(16) unsigned char smem[131072];
  const int tid = threadIdx.x;
  const int lane = tid & 63, w = tid >> 6;
  const int wm = w >> 2, wn = w & 3;   // 2M x 4N waves
  const int l15 = lane & 15;

  // T1: XCD-aware bijective swizzle (grid % 8 == 0 checked on host side)
  const int nbn = N >> 8;
  int bid = blockIdx.x;
  {
    const int nwg = gridDim.x;
    if ((nwg & 7) == 0) bid = (bid & 7) * (nwg >> 3) + (bid >> 3);
  }
  const int m0 = (bid / nbn) << 8;
  const int n0 = (bid % nbn) << 8;

  // LDS read offsets (within a 16 KiB unit): row*64 + swizzled 16B chunk
  const int chnk = (((lane >> 4) ^ ((l15 >> 1) & 3)) << 4);
  const int aoff = (wm * 128 + l15) * 64 + chnk;
  const int boff = (wn * 64 + l15) * 64 + chnk;

  // staging: thread -> (row = tid>>2 [+128 for 2nd load], logical chunk lc)
  const int rl = tid >> 2;
  const int lc = (tid & 3) ^ ((tid >> 3) & 3);  // inverse swizzle on source
  const unsigned short* pA = Xb + (size_t)(m0 + rl) * K + lc * 8;
  const unsigned short* pB = Wb + (size_t)(n0 + rl) * K + lc * 8;
  const int rstride = K << 7;   // 128 rows in elements
  const int wuo = w << 10;      // wave-uniform LDS dest offset (lane*16 by HW)

  f32x4 acc[8][4];
#pragma unroll
  for (int i = 0; i < 8; i++)
#pragma unroll
    for (int j = 0; j < 4; j++) acc[i][j] = (f32x4)(0.f);

  const int NT = K >> 6;

  // prologue: stage tile 0 -> buf 0, in-order A0,B0,A1,B1 (8 loads)
  stage2(pA, rstride, smem + wuo);
  stage2(pB, rstride, smem + 65536 + wuo);
  stage2(pA + 32, rstride, smem + 16384 + wuo);
  stage2(pB + 32, rstride, smem + 65536 + 16384 + wuo);
  WAIT_VMCNT(4);   // retire A0,B0; A1,B1 stay in flight
  wg_barrier();

  short8 av0, av1, av2, av3, bv0, bv1, bv2, bv3;

  for (int t = 0; t < NT - 1; ++t) {
    const int p = t & 1;
    const unsigned char* Ab = smem + p * 32768;
    const unsigned char* Bb = smem + 65536 + p * 32768;
    unsigned char* Aq = smem + (p ^ 1) * 32768 + wuo;
    unsigned char* Bq = smem + 65536 + (p ^ 1) * 32768 + wuo;
    const unsigned short* sA = pA + (size_t)(t + 1) * 64;
    const unsigned short* sB = pB + (size_t)(t + 1) * 64;

    // phase 1: mh0, ks0 | stage A-kh0(t+1)
    LDA(Ab, 0); LDB(Bb);
    stage2(sA, rstride, Aq);
    wg_barrier();
    PRIO1; MM16(0); PRIO0;
    wg_barrier();
    // phase 2: mh1, ks0 (B reused) | stage B-kh0(t+1)
    LDA(Ab, 1);
    stage2(sB, rstride, Bq);
    wg_barrier();
    PRIO1; MM16(4); PRIO0;
    WAIT_VMCNT(4);   // retire A-kh1,B-kh1 of tile t; keep t+1 kh0 units
    wg_barrier();
    // phase 3: mh0, ks1 | stage A-kh1(t+1)
    LDA(Ab + 16384, 0); LDB(Bb + 16384);
    stage2(sA + 32, rstride, Aq + 16384);
    wg_barrier();
    PRIO1; MM16(0); PRIO0;
    wg_barrier();
    // phase 4: mh1, ks1 (B reused) | stage B-kh1(t+1)
    LDA(Ab + 16384, 1);
    stage2(sB + 32, rstride, Bq + 16384);
    wg_barrier();
    PRIO1; MM16(4); PRIO0;
    WAIT_VMCNT(4);   // retire A-kh0,B-kh0 of tile t+1; keep its kh1 units
    wg_barrier();
  }

  // final tile (no staging): entering with its kh1 units still in flight
  {
    const int p = (NT - 1) & 1;
    const unsigned char* Ab = smem + p * 32768;
    const unsigned char* Bb = smem + 65536 + p * 32768;
    LDA(Ab, 0); LDB(Bb);
    wg_barrier();
    PRIO1; MM16(0); PRIO0;
    wg_barrier();
    LDA(Ab, 1);
    wg_barrier();
    PRIO1; MM16(4); PRIO0;
    WAIT_VMCNT(0);   // drain kh1 units (only non-counted wait in the kernel)
    wg_barrier();
    LDA(Ab + 16384, 0); LDB(Bb + 16384);
    wg_barrier();
    PRIO1; MM16(0); PRIO0;
    wg_barrier();
    LDA(Ab + 16384, 1);
    wg_barrier();
    PRIO1; MM16(4); PRIO0;
  }

  // epilogue: 16x16x32 C layout: col = lane&15, row = (lane>>4)*4 + reg
  const int gm = m0 + wm * 128 + ((lane >> 4) << 2);
  const int gn = n0 + wn * 64 + l15;
  float bvs[4];
#pragma unroll
  for (int g = 0; g < 4; ++g) bvs[g] = bias[gn + g * 16];
#pragma unroll
  for (int mf = 0; mf < 8; ++mf) {
    const size_t rb = (size_t)(gm + mf * 16) * N + gn;
#pragma unroll
    for (int r = 0; r < 4; ++r) {
#pragma unroll
      for (int g = 0; g < 4; ++g)
        C[rb + (size_t)r * N + g * 16] = acc[mf][g][r] + bvs[g];
    }
  }
}

// ---- fallback: fused dequant GEMM (odd shapes / tiny ws; never bounded) --
#define BM 128
#define BN 128
#define BK 64

__global__ __launch_bounds__(256) void gemm_fused(
    const float* __restrict__ Xf, const int* __restrict__ Wq,
    const float* __restrict__ Ws, const float* __restrict__ bias,
    float* __restrict__ C, int M, int N, int K) {
  __shared__ unsigned char smem[(BM * BK + BN * BK) * 2];
  const int tid = threadIdx.x;
  const int lane = tid & 63, wid = tid >> 6;
  const int m0 = blockIdx.y * BM, n0 = blockIdx.x * BN;
  const int sr = lane >> 3, fc = (lane & 7) ^ sr;
  const int arow = m0 + wid * 32 + sr, brow = n0 + wid * 32 + sr;
  unsigned char* As = smem;
  unsigned char* Bs = smem + BM * BK * 2;
  unsigned char* stA = As + wid * 4096 + lane * 16;
  unsigned char* stB = Bs + wid * 4096 + lane * 16;
  const int l31 = lane & 31, lh = lane >> 5, le = lane & 7;
  const int wm = (wid & 1) * 64, wn = (wid >> 1) * 64;
  const unsigned char* Aw = As + (wm + l31) * 128;
  const unsigned char* Bw = Bs + (wn + l31) * 128;
  const int Kg = K >> 6;

  f32x16 acc[2][2];
#pragma unroll
  for (int i = 0; i < 2; i++)
#pragma unroll
    for (int j = 0; j < 2; j++) acc[i][j] = (f32x16)(0.f);

  for (int k0 = 0; k0 < K; k0 += BK) {
#pragma unroll
    for (int t = 0; t < 4; t++) {
      const float4v* xa = (const float4v*)(Xf + (size_t)(arow + t * 8) * K + k0 + fc * 8);
      float4v x0 = xa[0], x1 = xa[1];
      ushort8 ra;
      ra[0] = f2bf(x0[0]); ra[1] = f2bf(x0[1]); ra[2] = f2bf(x0[2]); ra[3] = f2bf(x0[3]);
      ra[4] = f2bf(x1[0]); ra[5] = f2bf(x1[1]); ra[6] = f2bf(x1[2]); ra[7] = f2bf(x1[3]);
      *(ushort8*)(stA + t * 1024) = ra;
      const int4v* wq = (const int4v*)(Wq + (size_t)(brow + t * 8) * K + k0 + fc * 8);
      int4v q0 = wq[0], q1 = wq[1];
      float sc = Ws[(size_t)(brow + t * 8) * Kg + (k0 >> 6)];
      ushort8 rb;
      rb[0] = f2bf((float)q0[0] * sc); rb[1] = f2bf((float)q0[1] * sc);
      rb[2] = f2bf((float)q0[2] * sc); rb[3] = f2bf((float)q0[3] * sc);
      rb[4] = f2bf((float)q1[0] * sc); rb[5] = f2bf((float)q1[1] * sc);
      rb[6] = f2bf((float)q1[2] * sc); rb[7] = f2bf((float)q1[3] * sc);
      *(ushort8*)(stB + t * 1024) = rb;
    }
    __syncthreads();
#pragma unroll
    for (int s = 0; s < 4; s++) {
      const int off = ((s + 4 * lh) ^ le) << 4;
      short8 a0 = *(const short8*)(Aw + off);
      short8 a1 = *(const short8*)(Aw + 4096 + off);
      short8 b0 = *(const short8*)(Bw + off);
      short8 b1 = *(const short8*)(Bw + 4096 + off);
      acc[0][0] = __builtin_amdgcn_mfma_f32_32x32x16_bf16(a0, b0, acc[0][0], 0, 0, 0);
      acc[0][1] = __builtin_amdgcn_mfma_f32_32x32x16_bf16(a0, b1, acc[0][1], 0, 0, 0);
      acc[1][0] = __builtin_amdgcn_mfma_f32_32x32x16_bf16(a1, b0, acc[1][0], 0, 0, 0);
      acc[1][1] = __builtin_amdgcn_mfma_f32_32x32x16_bf16(a1, b1, acc[1][1], 0, 0, 0);
    }
    __syncthreads();
  }

  const int gm = m0 + wm + 4 * lh, gn = n0 + wn + l31;
#pragma unroll
  for (int j = 0; j < 2; j++) {
    const int col = gn + j * 32;
    const float bv = bias[col];
#pragma unroll
    for (int i = 0; i < 2; i++) {
      const int rbase = gm + i * 32;
      f32x16 v = acc[i][j];
#pragma unroll
      for (int r = 0; r < 16; r++) {
        const int row = rbase + (r & 3) + 8 * (r >> 2);
        C[(size_t)row * N + col] = v[r] + bv;
      }
    }
  }
}

extern "C" void kernel_launch(void* const* d_in, const int* in_sizes, int n_in,
                              void* d_out, int out_size, void* d_ws, size_t ws_size,
                              hipStream_t stream) {
  const float* x = (const float*)d_in[0];
  const int* wq = (const int*)d_in[1];
  const float* wsc = (const float*)d_in[2];
  const float* bias = (const float*)d_in[3];
  float* out = (float*)d_out;

  const int N = in_sizes[3];            // D_out (bias length)
  const int K = in_sizes[1] / N;        // D_in
  const int M = in_sizes[0] / K;        // B*S

  const size_t needX = (size_t)M * K * 2;
  const size_t needW = (size_t)N * K * 2;
  const bool big = (M % 256 == 0) && (N % 256 == 0) && (K % 64 == 0) && (K >= 128);

  if (big && ws_size >= needX + needW) {
    unsigned short* Xb = (unsigned short*)d_ws;
    unsigned short* Wb = (unsigned short*)((char*)d_ws + needX);
    const int n8x = (M * K) / 8, n8w = (N * K) / 8;
    const int gx = (n8x + 255) / 256, gw = (n8w + 255) / 256;
    cvt_kernel<<<gx + gw, 256, 0, stream>>>(x, wq, wsc, Xb, Wb, n8x, n8w, gx);
    dim3 grid((M / 256) * (N / 256));
    gemm_8p<<<grid, 512, 0, stream>>>(Xb, Wb, bias, out, M, N, K);
  } else {
    dim3 grid(N / BN, M / BM), block(256);
    gemm_fused<<<grid, block, 0, stream>>>(x, wq, wsc, bias, out, M, N, K);
  }
}